// Round 6
// baseline (1361.112 us; speedup 1.0000x reference)
//
#include <hip/hip_runtime.h>
#include <stdint.h>

#define NN 50000
#define QWORDS 25600000   // N*F words; q_out region. mu_out region starts here.

typedef __attribute__((ext_vector_type(8))) short bf16x8;
typedef __attribute__((ext_vector_type(4))) float f32x4;

__device__ __forceinline__ uint32_t f2bf(float x){
  uint32_t u = __builtin_bit_cast(uint32_t, x);
  u += 0x7FFFu + ((u >> 16) & 1u);          // RNE
  return u >> 16;
}
__device__ __forceinline__ float bf2f(uint32_t b){
  uint32_t u = b << 16;
  return __builtin_bit_cast(float, u);
}
__device__ __forceinline__ void gload16(const uint16_t* g, uint16_t* l){
  __builtin_amdgcn_global_load_lds(
      (const __attribute__((address_space(1))) uint32_t*)g,
      (__attribute__((address_space(3))) uint32_t*)l, 16, 0, 0);
}
__device__ __forceinline__ f32x4 mfma16(bf16x8 a, bf16x8 b, f32x4 c){
  return __builtin_amdgcn_mfma_f32_16x16x32_bf16(a, b, c, 0, 0, 0);
}

// ---------------- K0: weights f32 -> bf16 into ws ----------------
// layout (u16): [0,524288) W_mix | [524288,1048576) W1 | [1048576,1835008) W2
__global__ void k_convert(const float* __restrict__ wmix, const float* __restrict__ w1,
                          const float* __restrict__ w2, uint16_t* __restrict__ dst){
  int i = blockIdx.x * 256 + threadIdx.x;   // float4 index; grid covers exactly 458752
  int e = i << 2;
  const float* s; int o;
  if (e < 524288)       { s = wmix; o = e; }
  else if (e < 1048576) { s = w1;   o = e - 524288; }
  else                  { s = w2;   o = e - 1048576; }
  f32x4 v = *(const f32x4*)(s + o);
  uint2 pk;
  pk.x = f2bf(v[0]) | (f2bf(v[1]) << 16);
  pk.y = f2bf(v[2]) | (f2bf(v[3]) << 16);
  *(uint2*)(dst + e) = pk;
}

// ---------------- K1 v2 (round-3 proven): 512t blocks, f32 muW ---------------
__global__ __launch_bounds__(512, 4)
void k_gemm1(const float* __restrict__ mu, const uint16_t* __restrict__ wmixb,
             uint16_t* __restrict__ qh, float* __restrict__ muW){
  __shared__ uint16_t As[2][12288];   // 192x64 (r = d*64+nrow), 2x24KB
  __shared__ uint16_t Bs[2][8192];    // 128x64, 2x16KB
  const int tid  = threadIdx.x;
  const int lane = tid & 63;
  const int w    = tid >> 6;          // 0..7
  const int wn   = w & 3;             // n-quarter (16 rows)
  const int wf   = w >> 2;            // f-half (2 col-pairs)
  const int orig = blockIdx.x;
  const int j    = (orig & 7) * 782 + (orig >> 3);   // bijective XCD chunking
  const int f0   = (j & 7) * 64;
  const int n0   = (j >> 3) * 64;
  const int lrow = tid >> 4;          // 0..31
  const int lcol = (tid & 15) * 4;    // f32/u16 col base

  f32x4 ar[6];
  auto A_LOAD = [&](int ks){
    const int k0 = ks * 64;
    #pragma unroll
    for (int p=0; p<6; ++p){
      int r = p*32 + lrow;            // 0..191 = d*64 + nrow
      int d = r >> 6, nrow = r & 63;
      int n = n0 + nrow;
      int g = (n < NN ? n : NN-1)*3 + d;
      ar[p] = *(const f32x4*)(mu + (size_t)g*512 + k0 + lcol);
    }
  };
  auto A_WRITE = [&](int buf){
    #pragma unroll
    for (int p=0; p<6; ++p){
      int r = p*32 + lrow;
      f32x4 v = ar[p];
      uint2 pk;
      pk.x = f2bf(v[0]) | (f2bf(v[1]) << 16);
      pk.y = f2bf(v[2]) | (f2bf(v[3]) << 16);
      *(uint2*)&As[buf][r*64 + (lcol ^ ((r&7)<<3))] = pk;
    }
  };
  auto B_ISSUE = [&](int ks, int buf){
    const int k0 = ks * 64;
    #pragma unroll
    for (int jj=0; jj<2; ++jj){
      int jb = w*2 + jj;                 // 0..15
      int row = jb*8 + (lane>>3);
      int g = (row < 64) ? (f0 + row) : (448 + f0 + row);
      int srcc = ((lane&7) ^ ((lane>>3)&7)) * 8;
      gload16(wmixb + (size_t)g*512 + k0 + srcc, &Bs[buf][jb*512]);
    }
  };

  const f32x4 z4 = {0.f,0.f,0.f,0.f};
  f32x4 acc[3][4];                     // [d][{V0,V1,W0,W1}]
  #pragma unroll
  for (int d=0; d<3; ++d)
    #pragma unroll
    for (int nt=0; nt<4; ++nt) acc[d][nt] = z4;

  A_LOAD(0); B_ISSUE(0, 0); A_WRITE(0);
  for (int ks=0; ks<8; ++ks){
    const int cur = ks & 1;
    __syncthreads();
    if (ks < 7){ A_LOAD(ks+1); B_ISSUE(ks+1, cur^1); }
    #pragma unroll
    for (int kf=0; kf<2; ++kf){
      int kc = kf*32 + (lane>>4)*8;
      bf16x8 af[3];
      #pragma unroll
      for (int d=0; d<3; ++d){
        int r = d*64 + wn*16 + (lane&15);
        af[d] = *(const bf16x8*)&As[cur][r*64 + (kc ^ ((r&7)<<3))];
      }
      #pragma unroll
      for (int nt=0; nt<4; ++nt){
        int ntg = wf*2 + (nt&1) + (nt>>1)*4;   // {wf*2, wf*2+1, wf*2+4, wf*2+5}
        int rr = ntg*16 + (lane&15);
        bf16x8 bf = *(const bf16x8*)&Bs[cur][rr*64 + (kc ^ ((rr&7)<<3))];
        #pragma unroll
        for (int d=0; d<3; ++d)
          acc[d][nt] = mfma16(af[d], bf, acc[d][nt]);
      }
    }
    if (ks < 7) A_WRITE(cur^1);
  }

  const int rb4 = (lane >> 4) * 4;
  #pragma unroll
  for (int c=0; c<2; ++c){
    #pragma unroll
    for (int jx=0; jx<4; ++jx){
      int n = n0 + wn*16 + rb4 + jx;
      if (n >= NN) continue;
      int f = f0 + (wf*2 + c)*16 + (lane & 15);
      float v0 = acc[0][c][jx],   v1 = acc[1][c][jx],   v2 = acc[2][c][jx];
      float u0 = acc[0][c+2][jx], u1 = acc[1][c+2][jx], u2 = acc[2][c+2][jx];
      float vn = sqrtf(v0*v0 + v1*v1 + v2*v2 + 1e-8f);
      float dt = v0*u0 + v1*u1 + v2*u2;
      qh[(size_t)n*1024 + f]       = (uint16_t)f2bf(vn);
      qh[(size_t)n*1024 + 512 + f] = (uint16_t)f2bf(dt);
      size_t mb = (size_t)n*1536 + f;
      muW[mb] = u0; muW[mb+512] = u1; muW[mb+1024] = u2;
    }
  }
}

// ---------------- K2: h = silu(ctx @ W1^T) (unchanged, proven) ----------------
__global__ __launch_bounds__(256, 2)
void k_gemm2(const float* __restrict__ q, const uint16_t* __restrict__ w1b,
             const float* __restrict__ b1, uint16_t* __restrict__ qh){
  __shared__ uint16_t A2[2][2048];    // 64x32, 2x4KB
  __shared__ uint16_t B2[2][16384];   // 512x32, 2x32KB
  const int tid  = threadIdx.x;
  const int lane = tid & 63;
  const int w    = tid >> 6;
  const int wm   = w >> 1;            // 0..1
  const int wn   = w & 1;             // 0..1
  const int n0   = blockIdx.x * 64;

  f32x4 qa0, qa1;
  auto QA_LOAD = [&](int s){          // s<16: q f32
    int k0 = s*32;
    int row = tid >> 2, ch = tid & 3;
    int nc = (n0 + row < NN) ? n0 + row : NN-1;
    qa0 = *(const f32x4*)(q + (size_t)nc*512 + k0 + ch*8);
    qa1 = *(const f32x4*)(q + (size_t)nc*512 + k0 + ch*8 + 4);
  };
  auto QA_WRITE = [&](int buf){
    int row = tid >> 2, ch = tid & 3;
    uint4 pk;
    pk.x = f2bf(qa0[0]) | (f2bf(qa0[1]) << 16);
    pk.y = f2bf(qa0[2]) | (f2bf(qa0[3]) << 16);
    pk.z = f2bf(qa1[0]) | (f2bf(qa1[1]) << 16);
    pk.w = f2bf(qa1[2]) | (f2bf(qa1[3]) << 16);
    *(uint4*)&A2[buf][row*32 + ((ch ^ (row&3)))*8] = pk;
  };
  auto VA_ISSUE = [&](int s, int buf){ // s>=16: vn bf16 via gload
    int k0v = (s-16)*32;
    int row = w*16 + (lane>>2);
    int nc = (n0 + row < NN) ? n0 + row : NN-1;
    int srcch = (lane&3) ^ (row&3);
    gload16(qh + (size_t)nc*1024 + k0v + srcch*8, &A2[buf][w*512]);
  };
  auto B_ISSUE = [&](int s, int buf){
    int k0 = s*32;
    #pragma unroll
    for (int jj=0; jj<8; ++jj){
      int j = w*8 + jj;               // 0..31, rows j*16..+16
      int row = j*16 + (lane>>2);
      int srcch = (lane&3) ^ (row&3);
      gload16(w1b + (size_t)row*1024 + k0 + srcch*8, &B2[buf][j*512]);
    }
  };

  const f32x4 z4 = {0.f,0.f,0.f,0.f};
  f32x4 acc2[2][16];
  #pragma unroll
  for (int mt=0; mt<2; ++mt)
    #pragma unroll
    for (int nt=0; nt<16; ++nt) acc2[mt][nt] = z4;

  QA_LOAD(0); B_ISSUE(0, 0); QA_WRITE(0);
  for (int s=0; s<32; ++s){
    const int cur = s & 1;
    __syncthreads();
    if (s < 31){
      if (s+1 < 16) QA_LOAD(s+1); else VA_ISSUE(s+1, cur^1);
      B_ISSUE(s+1, cur^1);
    }
    {
      int kc = (lane>>4)*8;
      bf16x8 a[2];
      #pragma unroll
      for (int mt=0; mt<2; ++mt){
        int r = wm*32 + mt*16 + (lane&15);
        a[mt] = *(const bf16x8*)&A2[cur][r*32 + (kc ^ ((r&3)<<3))];
      }
      #pragma unroll
      for (int nt=0; nt<16; ++nt){
        int rr = wn*256 + nt*16 + (lane&15);
        bf16x8 b = *(const bf16x8*)&B2[cur][rr*32 + (kc ^ ((rr&3)<<3))];
        acc2[0][nt] = mfma16(a[0], b, acc2[0][nt]);
        acc2[1][nt] = mfma16(a[1], b, acc2[1][nt]);
      }
    }
    if (s < 31 && s+1 < 16) QA_WRITE(cur^1);
  }

  const int rb4 = (lane >> 4) * 4;
  #pragma unroll
  for (int nt=0; nt<16; ++nt){
    int col = wn*256 + nt*16 + (lane&15);
    float bb = b1[col];
    #pragma unroll
    for (int mt=0; mt<2; ++mt)
      #pragma unroll
      for (int j=0; j<4; ++j){
        int n = n0 + wm*32 + mt*16 + rb4 + j;
        if (n < NN){
          float x = acc2[mt][nt][j] + bb;
          float sv = x / (1.f + __expf(-x));
          qh[(size_t)n*1024 + col] = (uint16_t)f2bf(sv);
        }
      }
  }
}

// ---------------- K3 v7: barrier-free, h+dt fully LDS-staged -----------------
// Race fix vs v6: q_out writes (dout[n*512+fq]) alias qh u16 [2fq,2fq+2) --
// for fq>=256 that clobbers the dt region other threads still need. Stage the
// ENTIRE qh row (h[512] + dt[512] = 2KB/row, 64KB for 32 rows) into LDS,
// drained by vmcnt(0) + one barrier BEFORE any write. After that every global
// access is an input (q, mu), thread-own in-place (muW->mu_out, same thread,
// same address), or a write -> no ordering needed, zero barriers in main loop.
// B (W2, 1.5MB, L2-resident) loads straight to VGPRs, 2-deep double-buffered.
// grid = ceil(NN/32) = 1563. LDS 64KB -> 2 blocks/CU.
__global__ __launch_bounds__(512, 4)
void k_gemm3(const float* __restrict__ q, const float* __restrict__ mu,
             const uint16_t* __restrict__ w2b, const float* __restrict__ b2,
             float* __restrict__ dout){
  __shared__ uint16_t Hs[32*1024];    // 64KB: per row, [0,512)=h, [512,1024)=dt
  const int tid  = threadIdx.x;
  const int lane = tid & 63;
  const int w    = tid >> 6;          // 0..7
  const int wm   = w >> 2;            // 0..1 (16-row half)
  const int wn   = w & 3;             // 0..3 (16-col group in each 64-strip)
  const int n0   = blockIdx.x * 32;
  const uint16_t* qh = (const uint16_t*)dout;
  float* mout = dout + (size_t)QWORDS;
  const int l15 = lane & 15;
  const int rb4 = (lane >> 4) * 4;
  const int kof = (lane >> 4) * 8;    // k sub-offset within fragment (u16)

  // prologue: full qh-row preload (8 issues/wave: 4 rows x {h,dt}), ONE barrier
  #pragma unroll
  for (int i=0; i<4; ++i){
    int row = w*4 + i;
    int nc = (n0 + row < NN) ? n0 + row : NN-1;
    int sc = (lane ^ (row&7)) * 8;
    gload16(qh + (size_t)nc*1024 + sc,       &Hs[row*1024]);
    gload16(qh + (size_t)nc*1024 + 512 + sc, &Hs[row*1024 + 512]);
  }
  asm volatile("s_waitcnt vmcnt(0)" ::: "memory");
  __syncthreads();

  int nidx[4], rowp[4];
  #pragma unroll
  for (int p=0; p<4; ++p){
    int rr = wm*16 + rb4 + p;
    rowp[p] = rr;
    int n = n0 + rr;
    nidx[p] = n < NN ? n : NN-1;
  }

  #pragma unroll 1
  for (int it=0; it<8; ++it){
    const int fq = it*64 + wn*16 + l15;
    const float bb0 = b2[fq], bb1 = b2[512+fq], bb2 = b2[1024+fq];
    float qv[4], dtv[4], muv[3][4], mwv[3][4];
    const int dc = fq >> 3, dо = fq & 7;
    #pragma unroll
    for (int p=0; p<4; ++p){
      // dt from LDS (chunk XOR-swizzled per row)
      dtv[p] = bf2f(Hs[rowp[p]*1024 + 512 + ((dc ^ (rowp[p]&7))*8) + dо]);
      qv[p]  = q[(size_t)nidx[p]*512 + fq];
      size_t mb = (size_t)nidx[p]*1536 + fq;
      muv[0][p] = mu[mb];   muv[1][p] = mu[mb+512];   muv[2][p] = mu[mb+1024];
      mwv[0][p] = mout[mb]; mwv[1][p] = mout[mb+512]; mwv[2][p] = mout[mb+1024];
    }

    f32x4 acc0 = {0.f,0.f,0.f,0.f}, acc1 = acc0, acc2 = acc0;
    const uint16_t* bp0 = w2b + (size_t)(it*64 + wn*16 + l15)*512;  // strip-0 row
    bf16x8 bc[6], bn[6];
    auto LDB = [&](bf16x8* dst, int ks){
      const int ko = ks*64 + kof;
      #pragma unroll
      for (int s3=0; s3<3; ++s3){
        const uint16_t* bp = bp0 + (size_t)s3*512*512;
        dst[s3*2+0] = *(const bf16x8*)(bp + ko);        // kf=0
        dst[s3*2+1] = *(const bf16x8*)(bp + ko + 32);   // kf=1
      }
    };
    LDB(bc, 0);
    #pragma unroll
    for (int ks=0; ks<8; ++ks){
      if (ks < 7) LDB(bn, ks+1);
      const int r = wm*16 + l15;
      const int ch0 = (ks*8 + 0 + (lane>>4)) ^ (r&7);
      const int ch1 = (ks*8 + 4 + (lane>>4)) ^ (r&7);
      bf16x8 a0 = *(const bf16x8*)&Hs[r*1024 + ch0*8];
      bf16x8 a1 = *(const bf16x8*)&Hs[r*1024 + ch1*8];
      acc0 = mfma16(a0, bc[0], acc0); acc0 = mfma16(a1, bc[1], acc0);
      acc1 = mfma16(a0, bc[2], acc1); acc1 = mfma16(a1, bc[3], acc1);
      acc2 = mfma16(a0, bc[4], acc2); acc2 = mfma16(a1, bc[5], acc2);
      #pragma unroll
      for (int z=0; z<6; ++z) bc[z] = bn[z];
    }

    #pragma unroll
    for (int p=0; p<4; ++p){
      int n = n0 + wm*16 + rb4 + p;
      if (n < NN){
        float x0 = acc0[p] + bb0;
        float x1 = acc1[p] + bb1;
        float x2 = acc2[p] + bb2;
        dout[(size_t)n*512 + fq] = qv[p] + x0 + x2*dtv[p];
        size_t mb = (size_t)n*1536 + fq;
        mout[mb]      = muv[0][p] + x1*mwv[0][p];
        mout[mb+512]  = muv[1][p] + x1*mwv[1][p];
        mout[mb+1024] = muv[2][p] + x1*mwv[2][p];
      }
    }
  }
}

extern "C" void kernel_launch(void* const* d_in, const int* in_sizes, int n_in,
                              void* d_out, int out_size, void* d_ws, size_t ws_size,
                              hipStream_t stream){
  (void)in_sizes; (void)n_in; (void)out_size; (void)ws_size;
  const float* q    = (const float*)d_in[0];
  const float* mu   = (const float*)d_in[1];
  const float* wmix = (const float*)d_in[2];
  const float* w1   = (const float*)d_in[3];
  const float* b1   = (const float*)d_in[4];
  const float* w2   = (const float*)d_in[5];
  const float* b2   = (const float*)d_in[6];
  uint16_t* wb = (uint16_t*)d_ws;
  float* dout = (float*)d_out;

  hipLaunchKernelGGL(k_convert, dim3(1792), dim3(256), 0, stream, wmix, w1, w2, wb);
  hipLaunchKernelGGL(k_gemm1, dim3(6256), dim3(512), 0, stream,
                     mu, wb, (uint16_t*)d_out, dout + (size_t)QWORDS);
  hipLaunchKernelGGL(k_gemm2, dim3(782), dim3(256), 0, stream,
                     q, wb + 524288, b1, (uint16_t*)d_out);
  hipLaunchKernelGGL(k_gemm3, dim3(1563), dim3(512), 0, stream,
                     q, mu, wb + 1048576, b2, dout);
}

// Round 7
// 893.419 us; speedup vs baseline: 1.5235x; 1.5235x over previous
//
#include <hip/hip_runtime.h>
#include <stdint.h>

#define NN 50000
#define QWORDS 25600000   // N*F words; q_out region. mu_out region starts here.

typedef __attribute__((ext_vector_type(8))) short bf16x8;
typedef __attribute__((ext_vector_type(4))) float f32x4;

__device__ __forceinline__ uint32_t f2bf(float x){
  uint32_t u = __builtin_bit_cast(uint32_t, x);
  u += 0x7FFFu + ((u >> 16) & 1u);          // RNE
  return u >> 16;
}
__device__ __forceinline__ float bf2f(uint32_t b){
  uint32_t u = b << 16;
  return __builtin_bit_cast(float, u);
}
__device__ __forceinline__ void gload16(const uint16_t* g, uint16_t* l){
  __builtin_amdgcn_global_load_lds(
      (const __attribute__((address_space(1))) uint32_t*)g,
      (__attribute__((address_space(3))) uint32_t*)l, 16, 0, 0);
}
__device__ __forceinline__ f32x4 mfma16(bf16x8 a, bf16x8 b, f32x4 c){
  return __builtin_amdgcn_mfma_f32_16x16x32_bf16(a, b, c, 0, 0, 0);
}

#define FENCE() asm volatile("" ::: "memory")

// ---------------- K0: weights f32 -> bf16 into ws ----------------
// layout (u16): [0,524288) W_mix | [524288,1048576) W1 | [1048576,1835008) W2
__global__ void k_convert(const float* __restrict__ wmix, const float* __restrict__ w1,
                          const float* __restrict__ w2, uint16_t* __restrict__ dst){
  int i = blockIdx.x * 256 + threadIdx.x;   // float4 index; grid covers exactly 458752
  int e = i << 2;
  const float* s; int o;
  if (e < 524288)       { s = wmix; o = e; }
  else if (e < 1048576) { s = w1;   o = e - 524288; }
  else                  { s = w2;   o = e - 1048576; }
  f32x4 v = *(const f32x4*)(s + o);
  uint2 pk;
  pk.x = f2bf(v[0]) | (f2bf(v[1]) << 16);
  pk.y = f2bf(v[2]) | (f2bf(v[3]) << 16);
  *(uint2*)(dst + e) = pk;
}

// ---------------- K1 v2 (round-3 proven): 512t blocks, f32 muW ---------------
__global__ __launch_bounds__(512, 4)
void k_gemm1(const float* __restrict__ mu, const uint16_t* __restrict__ wmixb,
             uint16_t* __restrict__ qh, float* __restrict__ muW){
  __shared__ uint16_t As[2][12288];   // 192x64 (r = d*64+nrow), 2x24KB
  __shared__ uint16_t Bs[2][8192];    // 128x64, 2x16KB
  const int tid  = threadIdx.x;
  const int lane = tid & 63;
  const int w    = tid >> 6;          // 0..7
  const int wn   = w & 3;             // n-quarter (16 rows)
  const int wf   = w >> 2;            // f-half (2 col-pairs)
  const int orig = blockIdx.x;
  const int j    = (orig & 7) * 782 + (orig >> 3);   // bijective XCD chunking
  const int f0   = (j & 7) * 64;
  const int n0   = (j >> 3) * 64;
  const int lrow = tid >> 4;          // 0..31
  const int lcol = (tid & 15) * 4;    // f32/u16 col base

  f32x4 ar[6];
  auto A_LOAD = [&](int ks){
    const int k0 = ks * 64;
    #pragma unroll
    for (int p=0; p<6; ++p){
      int r = p*32 + lrow;            // 0..191 = d*64 + nrow
      int d = r >> 6, nrow = r & 63;
      int n = n0 + nrow;
      int g = (n < NN ? n : NN-1)*3 + d;
      ar[p] = *(const f32x4*)(mu + (size_t)g*512 + k0 + lcol);
    }
  };
  auto A_WRITE = [&](int buf){
    #pragma unroll
    for (int p=0; p<6; ++p){
      int r = p*32 + lrow;
      f32x4 v = ar[p];
      uint2 pk;
      pk.x = f2bf(v[0]) | (f2bf(v[1]) << 16);
      pk.y = f2bf(v[2]) | (f2bf(v[3]) << 16);
      *(uint2*)&As[buf][r*64 + (lcol ^ ((r&7)<<3))] = pk;
    }
  };
  auto B_ISSUE = [&](int ks, int buf){
    const int k0 = ks * 64;
    #pragma unroll
    for (int jj=0; jj<2; ++jj){
      int jb = w*2 + jj;                 // 0..15
      int row = jb*8 + (lane>>3);
      int g = (row < 64) ? (f0 + row) : (448 + f0 + row);
      int srcc = ((lane&7) ^ ((lane>>3)&7)) * 8;
      gload16(wmixb + (size_t)g*512 + k0 + srcc, &Bs[buf][jb*512]);
    }
  };

  const f32x4 z4 = {0.f,0.f,0.f,0.f};
  f32x4 acc[3][4];                     // [d][{V0,V1,W0,W1}]
  #pragma unroll
  for (int d=0; d<3; ++d)
    #pragma unroll
    for (int nt=0; nt<4; ++nt) acc[d][nt] = z4;

  A_LOAD(0); B_ISSUE(0, 0); A_WRITE(0);
  for (int ks=0; ks<8; ++ks){
    const int cur = ks & 1;
    __syncthreads();
    if (ks < 7){ A_LOAD(ks+1); B_ISSUE(ks+1, cur^1); }
    #pragma unroll
    for (int kf=0; kf<2; ++kf){
      int kc = kf*32 + (lane>>4)*8;
      bf16x8 af[3];
      #pragma unroll
      for (int d=0; d<3; ++d){
        int r = d*64 + wn*16 + (lane&15);
        af[d] = *(const bf16x8*)&As[cur][r*64 + (kc ^ ((r&7)<<3))];
      }
      #pragma unroll
      for (int nt=0; nt<4; ++nt){
        int ntg = wf*2 + (nt&1) + (nt>>1)*4;   // {wf*2, wf*2+1, wf*2+4, wf*2+5}
        int rr = ntg*16 + (lane&15);
        bf16x8 bf = *(const bf16x8*)&Bs[cur][rr*64 + (kc ^ ((rr&7)<<3))];
        #pragma unroll
        for (int d=0; d<3; ++d)
          acc[d][nt] = mfma16(af[d], bf, acc[d][nt]);
      }
    }
    if (ks < 7) A_WRITE(cur^1);
  }

  const int rb4 = (lane >> 4) * 4;
  #pragma unroll
  for (int c=0; c<2; ++c){
    #pragma unroll
    for (int jx=0; jx<4; ++jx){
      int n = n0 + wn*16 + rb4 + jx;
      if (n >= NN) continue;
      int f = f0 + (wf*2 + c)*16 + (lane & 15);
      float v0 = acc[0][c][jx],   v1 = acc[1][c][jx],   v2 = acc[2][c][jx];
      float u0 = acc[0][c+2][jx], u1 = acc[1][c+2][jx], u2 = acc[2][c+2][jx];
      float vn = sqrtf(v0*v0 + v1*v1 + v2*v2 + 1e-8f);
      float dt = v0*u0 + v1*u1 + v2*u2;
      qh[(size_t)n*1024 + f]       = (uint16_t)f2bf(vn);
      qh[(size_t)n*1024 + 512 + f] = (uint16_t)f2bf(dt);
      size_t mb = (size_t)n*1536 + f;
      muW[mb] = u0; muW[mb+512] = u1; muW[mb+1024] = u2;
    }
  }
}

// ---------------- K2 v2: 512 threads, same 64x512 tile -> 16 waves/CU --------
// Same tiling/LDS (72KB) as proven K2, but 8 waves/block: wm=w>>2 row-half,
// wn=w&3 f-quarter (acc 2x8 = 64 VGPR, was 2x16=128). 2 blocks/CU x 8 waves.
// A-staging: row=tid>>3, ch=tid&7 (one f32x4/thread); chunk-XOR swizzle kept.
// VA gloads by waves 0..3 only (4KB region); B 4 issues/wave (32KB).
__global__ __launch_bounds__(512, 4)
void k_gemm2(const float* __restrict__ q, const uint16_t* __restrict__ w1b,
             const float* __restrict__ b1, uint16_t* __restrict__ qh){
  __shared__ uint16_t A2[2][2048];    // 64x32, 2x4KB
  __shared__ uint16_t B2[2][16384];   // 512x32, 2x32KB
  const int tid  = threadIdx.x;
  const int lane = tid & 63;
  const int w    = tid >> 6;          // 0..7
  const int wm   = w >> 2;            // 0..1 (32-row half)
  const int wn   = w & 3;             // 0..3 (128-col quarter)
  const int n0   = blockIdx.x * 64;

  f32x4 qa;
  auto QA_LOAD = [&](int s){          // s<16: q f32, one f32x4/thread
    int k0 = s*32;
    int row = tid >> 3, ch = tid & 7;
    int nc = (n0 + row < NN) ? n0 + row : NN-1;
    qa = *(const f32x4*)(q + (size_t)nc*512 + k0 + ch*4);
  };
  auto QA_WRITE = [&](int buf){
    int row = tid >> 3, ch = tid & 7;
    uint2 pk;
    pk.x = f2bf(qa[0]) | (f2bf(qa[1]) << 16);
    pk.y = f2bf(qa[2]) | (f2bf(qa[3]) << 16);
    // chunk c = ch>>1 (8 u16) placed at (c ^ (row&3)); half = ch&1
    *(uint2*)&A2[buf][row*32 + (((ch>>1) ^ (row&3))<<3) + (ch&1)*4] = pk;
  };
  auto VA_ISSUE = [&](int s, int buf){ // s>=16: vn bf16 via gload, waves 0..3
    if (w < 4){
      int k0v = (s-16)*32;
      int row = w*16 + (lane>>2);
      int nc = (n0 + row < NN) ? n0 + row : NN-1;
      int srcch = (lane&3) ^ (row&3);
      gload16(qh + (size_t)nc*1024 + k0v + srcch*8, &A2[buf][w*512]);
    }
  };
  auto B_ISSUE = [&](int s, int buf){
    int k0 = s*32;
    #pragma unroll
    for (int jj=0; jj<4; ++jj){
      int j = w*4 + jj;               // 0..31, rows j*16..+16
      int row = j*16 + (lane>>2);
      int srcch = (lane&3) ^ (row&3);
      gload16(w1b + (size_t)row*1024 + k0 + srcch*8, &B2[buf][j*512]);
    }
  };

  const f32x4 z4 = {0.f,0.f,0.f,0.f};
  f32x4 acc2[2][8];
  #pragma unroll
  for (int mt=0; mt<2; ++mt)
    #pragma unroll
    for (int nt=0; nt<8; ++nt) acc2[mt][nt] = z4;

  QA_LOAD(0); B_ISSUE(0, 0); QA_WRITE(0);
  for (int s=0; s<32; ++s){
    const int cur = s & 1;
    __syncthreads();
    if (s < 31){
      if (s+1 < 16) QA_LOAD(s+1); else VA_ISSUE(s+1, cur^1);
      B_ISSUE(s+1, cur^1);
    }
    {
      int kc = (lane>>4)*8;
      bf16x8 a[2];
      #pragma unroll
      for (int mt=0; mt<2; ++mt){
        int r = wm*32 + mt*16 + (lane&15);
        a[mt] = *(const bf16x8*)&A2[cur][r*32 + (kc ^ ((r&3)<<3))];
      }
      #pragma unroll
      for (int nt=0; nt<8; ++nt){
        int rr = wn*128 + nt*16 + (lane&15);
        bf16x8 b = *(const bf16x8*)&B2[cur][rr*32 + (kc ^ ((rr&3)<<3))];
        acc2[0][nt] = mfma16(a[0], b, acc2[0][nt]);
        acc2[1][nt] = mfma16(a[1], b, acc2[1][nt]);
      }
    }
    if (s < 31 && s+1 < 16) QA_WRITE(cur^1);
  }

  const int rb4 = (lane >> 4) * 4;
  #pragma unroll
  for (int nt=0; nt<8; ++nt){
    int col = wn*128 + nt*16 + (lane&15);
    float bb = b1[col];
    #pragma unroll
    for (int mt=0; mt<2; ++mt)
      #pragma unroll
      for (int j=0; j<4; ++j){
        int n = n0 + wm*32 + mt*16 + rb4 + j;
        if (n < NN){
          float x = acc2[mt][nt][j] + bb;
          float sv = x / (1.f + __expf(-x));
          qh[(size_t)n*1024 + col] = (uint16_t)f2bf(sv);
        }
      }
  }
}

// ---------------- K3 v4 (round-3 proven): 32-row blocks, counted vmcnt -------
// grid MUST be ceil(NN/32) = 1563.
__global__ __launch_bounds__(512, 4)
void k_gemm3(const float* __restrict__ q, const float* __restrict__ mu,
             const uint16_t* __restrict__ w2b, const float* __restrict__ b2,
             float* __restrict__ dout){
  __shared__ uint16_t Hs[32*512];     // 32KB
  __shared__ uint16_t B3[2][12288];   // 2x24KB ring (192 rows x 64 k each)
  const int tid  = threadIdx.x;
  const int lane = tid & 63;
  const int w    = tid >> 6;          // 0..7
  const int wm   = w >> 2;            // 0..1 (16-row half)
  const int wn   = w & 3;             // 0..3 (16-col group in each 64-strip)
  const int n0   = blockIdx.x * 32;
  const uint16_t* qh = (const uint16_t*)dout;
  float* mout = dout + (size_t)QWORDS;
  const int l15 = lane & 15;
  const int rb4 = (lane >> 4) * 4;
  const f32x4 z4 = {0.f,0.f,0.f,0.f};

  // prologue: Hs preload (4 issues/wave, 32 rows)
  #pragma unroll
  for (int i=0; i<4; ++i){
    int row = w*4 + i;
    int nc = (n0 + row < NN) ? n0 + row : NN-1;
    gload16(qh + (size_t)nc*1024 + (size_t)((lane ^ (row&7))*8), &Hs[row*512]);
  }

  auto B_ISSUE = [&](int it, int ks, uint16_t* slot){
    #pragma unroll
    for (int jj=0; jj<3; ++jj){
      int j = w*3 + jj;               // 0..23
      int rr = j*8 + (lane>>3);       // 0..191
      int s3 = rr >> 6, fi = rr & 63;
      int g = s3*512 + it*64 + fi;
      gload16(w2b + (size_t)g*512 + ks*64 + ((lane&7) ^ (rr&7))*8, slot + j*512);
    }
  };
  B_ISSUE(0, 0, B3[0]);

  float dtv[4], qv[4], muv[3][4], mwv[3][4];
  float bb0=0.f, bb1=0.f, bb2=0.f;
  int   fq = 0;
  f32x4 acc3[3];

#define K3_MFMA(KS) do{ \
    const uint16_t* bsl = B3[(KS)&1]; \
    __builtin_amdgcn_s_setprio(1); \
    _Pragma("unroll") \
    for (int kf=0; kf<2; ++kf){ \
      int r = wm*16 + l15; \
      int ch = ((KS)*8 + kf*4 + (lane>>4)) ^ (r&7); \
      bf16x8 a = *(const bf16x8*)&Hs[r*512 + ch*8]; \
      _Pragma("unroll") \
      for (int s3=0; s3<3; ++s3){ \
        int rr = s3*64 + wn*16 + l15; \
        int chb = (kf*4 + (lane>>4)) ^ (rr&7); \
        bf16x8 b = *(const bf16x8*)&bsl[rr*64 + chb*8]; \
        acc3[s3] = mfma16(a, b, acc3[s3]); \
      } \
    } \
    __builtin_amdgcn_s_setprio(0); \
  } while(0)

  #pragma unroll 1
  for (int it=0; it<8; ++it){
    // ---- ks=0 ----
    if (it) { asm volatile("s_waitcnt vmcnt(16)" ::: "memory"); }
    else    { asm volatile("s_waitcnt vmcnt(0)"  ::: "memory"); }
    __builtin_amdgcn_s_barrier();
    B_ISSUE(it, 1, B3[1]);
    FENCE();
    {
      #pragma unroll
      for (int s3=0; s3<3; ++s3) acc3[s3] = z4;
      fq = it*64 + wn*16 + l15;
      bb0 = b2[fq]; bb1 = b2[512+fq]; bb2 = b2[1024+fq];
      #pragma unroll
      for (int p=0; p<4; ++p){
        int n = n0 + wm*16 + rb4 + p;
        int nc = n < NN ? n : NN-1;
        dtv[p] = bf2f(qh[(size_t)nc*1024 + 512 + fq]);
        qv[p]  = q[(size_t)nc*512 + fq];
      }
    }
    FENCE();
    K3_MFMA(0);

    // ---- ks=1 ----
    asm volatile("s_waitcnt vmcnt(11)" ::: "memory");
    __builtin_amdgcn_s_barrier();
    B_ISSUE(it, 2, B3[0]);
    FENCE();
    {
      #pragma unroll
      for (int p=0; p<4; ++p){
        int n = n0 + wm*16 + rb4 + p;
        int nc = n < NN ? n : NN-1;
        size_t mb = (size_t)nc*1536 + fq;
        muv[0][p] = mu[mb]; muv[1][p] = mu[mb+512]; muv[2][p] = mu[mb+1024];
      }
    }
    FENCE();
    K3_MFMA(1);

    // ---- ks=2 ----
    asm volatile("s_waitcnt vmcnt(12)" ::: "memory");
    __builtin_amdgcn_s_barrier();
    B_ISSUE(it, 3, B3[1]);
    FENCE();
    {
      #pragma unroll
      for (int p=0; p<4; ++p){
        int n = n0 + wm*16 + rb4 + p;
        int nc = n < NN ? n : NN-1;
        size_t mb = (size_t)nc*1536 + fq;
        mwv[0][p] = mout[mb]; mwv[1][p] = mout[mb+512]; mwv[2][p] = mout[mb+1024];
      }
    }
    FENCE();
    K3_MFMA(2);

    // ---- ks=3 ----
    asm volatile("s_waitcnt vmcnt(12)" ::: "memory");
    __builtin_amdgcn_s_barrier();
    B_ISSUE(it, 4, B3[0]);
    FENCE();
    K3_MFMA(3);

    // ---- ks=4 ----
    asm volatile("s_waitcnt vmcnt(0)" ::: "memory");
    __builtin_amdgcn_s_barrier();
    B_ISSUE(it, 5, B3[1]);
    FENCE();
    K3_MFMA(4);

    // ---- ks=5 ----
    asm volatile("s_waitcnt vmcnt(0)" ::: "memory");
    __builtin_amdgcn_s_barrier();
    B_ISSUE(it, 6, B3[0]);
    FENCE();
    K3_MFMA(5);

    // ---- ks=6 ----
    asm volatile("s_waitcnt vmcnt(0)" ::: "memory");
    __builtin_amdgcn_s_barrier();
    B_ISSUE(it, 7, B3[1]);
    FENCE();
    K3_MFMA(6);

    // ---- ks=7 ----
    asm volatile("s_waitcnt vmcnt(0)" ::: "memory");
    __builtin_amdgcn_s_barrier();
    if (it < 7) B_ISSUE(it+1, 0, B3[0]);
    FENCE();
    K3_MFMA(7);
    {
      #pragma unroll
      for (int p=0; p<4; ++p){
        int n = n0 + wm*16 + rb4 + p;
        if (n < NN){
          float x0 = acc3[0][p] + bb0;
          float x1 = acc3[1][p] + bb1;
          float x2 = acc3[2][p] + bb2;
          dout[(size_t)n*512 + fq] = qv[p] + x0 + x2*dtv[p];
          size_t mb = (size_t)n*1536 + fq;
          mout[mb]      = muv[0][p] + x1*mwv[0][p];
          mout[mb+512]  = muv[1][p] + x1*mwv[1][p];
          mout[mb+1024] = muv[2][p] + x1*mwv[2][p];
        }
      }
    }
  }
#undef K3_MFMA
}

extern "C" void kernel_launch(void* const* d_in, const int* in_sizes, int n_in,
                              void* d_out, int out_size, void* d_ws, size_t ws_size,
                              hipStream_t stream){
  (void)in_sizes; (void)n_in; (void)out_size; (void)ws_size;
  const float* q    = (const float*)d_in[0];
  const float* mu   = (const float*)d_in[1];
  const float* wmix = (const float*)d_in[2];
  const float* w1   = (const float*)d_in[3];
  const float* b1   = (const float*)d_in[4];
  const float* w2   = (const float*)d_in[5];
  const float* b2   = (const float*)d_in[6];
  uint16_t* wb = (uint16_t*)d_ws;
  float* dout = (float*)d_out;

  hipLaunchKernelGGL(k_convert, dim3(1792), dim3(256), 0, stream, wmix, w1, w2, wb);
  hipLaunchKernelGGL(k_gemm1, dim3(6256), dim3(512), 0, stream,
                     mu, wb, (uint16_t*)d_out, dout + (size_t)QWORDS);
  hipLaunchKernelGGL(k_gemm2, dim3(782), dim3(512), 0, stream,
                     q, wb + 524288, b1, (uint16_t*)d_out);
  hipLaunchKernelGGL(k_gemm3, dim3(1563), dim3(512), 0, stream,
                     q, mu, wb + 1048576, b2, dout);
}